// Round 13
// baseline (352.327 us; speedup 1.0000x reference)
//
#include <hip/hip_runtime.h>

typedef unsigned short u16;
typedef unsigned int u32;

using short8 = __attribute__((ext_vector_type(8))) short;
using f32x4  = __attribute__((ext_vector_type(4))) float;
using f32x2  = __attribute__((ext_vector_type(2))) float;

#define SSEQ 512
#define BB   16
#define DD   256
#define G4   256      // 4*SS
#define SSZ  64       // SS
#define VV   10000
#define VPAD 10112    // 79*128
#define MALL 8192     // BB*SSEQ

// ---- ws layout (bytes) ----
#define OFF_XHI   0u
#define OFF_XLO   4194304u
#define OFF_WHI   8388608u
#define OFF_WLO   8519680u
#define OFF_WSY   8650752u
#define OFF_XPROJ 9945088u
#define OFF_HS    18333696u

__device__ __forceinline__ u16 f2bf(float f) {
  u32 u = __float_as_uint(f);
  u32 r = (u + 0x7fffu + ((u >> 16) & 1u)) >> 16;
  return (u16)r;
}
__device__ __forceinline__ float bf2f(u16 h) {
  return __uint_as_float(((u32)h) << 16);
}
// packed dual-FMA: c += a*b elementwise
__device__ __forceinline__ f32x2 pkfma(f32x2 a, f32x2 b, f32x2 c) {
  asm("v_pk_fma_f32 %0, %1, %2, %0" : "+v"(c) : "v"(a), "v"(b));
  return c;
}
// quad butterfly add via DPP; CTRL 0xB1=xor1, 0x4E=xor2
template <int CTRL>
__device__ __forceinline__ float qadd(float x) {
  int pv = __builtin_amdgcn_update_dpp(0, __float_as_int(x), CTRL, 0xf, 0xf, true);
  return x + __int_as_float(pv);
}
// quad broadcast of lane: 0x00/0x55/0xAA/0xFF
template <int CTRL>
__device__ __forceinline__ float qbcast(float x) {
  int pv = __builtin_amdgcn_update_dpp(0, __float_as_int(x), CTRL, 0xf, 0xf, true);
  return __int_as_float(pv);
}

// ---------------- K0: fp32 -> bf16 (hi/lo split for x, Wxs; padded bf16 Wsy) ----
#define NX 2097152
#define NW 65536
#define NP 647168   // VPAD*64
__global__ void k0_convert(const float* __restrict__ x, const float* __restrict__ Wxs,
                           const float* __restrict__ Wsy,
                           u16* __restrict__ xhi, u16* __restrict__ xlo,
                           u16* __restrict__ whi, u16* __restrict__ wlo,
                           u16* __restrict__ wsyb) {
  int i = blockIdx.x * 256 + threadIdx.x;
  if (i < NX) {
    float v = x[i]; u16 h = f2bf(v);
    xhi[i] = h; xlo[i] = f2bf(v - bf2f(h));
  } else if (i < NX + NW) {
    int j = i - NX;
    float v = Wxs[j]; u16 h = f2bf(v);
    whi[j] = h; wlo[j] = f2bf(v - bf2f(h));
  } else if (i < NX + NW + NP) {
    int j = i - NX - NW;
    wsyb[j] = (j < VV * SSZ) ? f2bf(Wsy[j]) : (u16)0;
  }
}

// ---------------- K1: xproj = x @ Wxs^T + b   (double-bf16 MFMA, fp32 out) ------
__global__ __launch_bounds__(256) void k1_xproj(
    const u16* __restrict__ xhi, const u16* __restrict__ xlo,
    const u16* __restrict__ whi, const u16* __restrict__ wlo,
    const float* __restrict__ bias, float* __restrict__ xproj) {
  int bid = blockIdx.x;
  int mb = bid >> 1, nb = bid & 1;
  int tid = threadIdx.x, l = tid & 63, wid = tid >> 6;
  int wm = wid >> 1, wv = wid & 1;
  int m0 = mb * 128 + wm * 64, n0 = nb * 128 + wv * 64;
  int lr = l & 15, lg = l >> 4;

  f32x4 acc[4][4];
#pragma unroll
  for (int a = 0; a < 4; a++)
#pragma unroll
    for (int bq = 0; bq < 4; bq++) acc[a][bq] = (f32x4){0.f, 0.f, 0.f, 0.f};

#pragma unroll
  for (int p = 0; p < 3; p++) {
    const u16* A = (p == 1) ? xlo : xhi;
    const u16* B = (p == 2) ? wlo : whi;
#pragma unroll
    for (int ks = 0; ks < 8; ks++) {
      short8 af[4], bf_[4];
#pragma unroll
      for (int fm = 0; fm < 4; fm++)
        af[fm] = *(const short8*)(A + (size_t)(m0 + fm * 16 + lr) * 256 + ks * 32 + lg * 8);
#pragma unroll
      for (int fv = 0; fv < 4; fv++)
        bf_[fv] = *(const short8*)(B + (size_t)(n0 + fv * 16 + lr) * 256 + ks * 32 + lg * 8);
#pragma unroll
      for (int fm = 0; fm < 4; fm++)
#pragma unroll
        for (int fv = 0; fv < 4; fv++)
          acc[fm][fv] = __builtin_amdgcn_mfma_f32_16x16x32_bf16(af[fm], bf_[fv], acc[fm][fv], 0, 0, 0);
    }
  }
#pragma unroll
  for (int fv = 0; fv < 4; fv++) {
    int j = n0 + fv * 16 + lr;
    float bj = bias[j];
#pragma unroll
    for (int fm = 0; fm < 4; fm++)
#pragma unroll
      for (int r = 0; r < 4; r++) {
        int m = m0 + fm * 16 + lg * 4 + r;
        xproj[(size_t)m * 256 + j] = acc[fm][fv][r] + bj;
      }
  }
}

// ---------------- K2: serial LSTM scan. 8 blocks x 512 thr (2 batches/block) ---
// 2 waves/SIMD from INDEPENDENT batches -> one batch's issue hides the other's
// LDS-roundtrip/trans latency; each wave keeps a 256-VGPR budget so the 64
// weight VGPRs stay resident (R6's 1024-thr variant spilled at 128-budget).
// Per batch: R5 quad/k-split structure, one lgkm barrier/step (syncs both
// batches in lockstep — symmetric work), 4-deep xp prefetch, h written
// fire-and-forget to global (no vmcnt drain in loop).
__global__ __launch_bounds__(512, 1) void k2_scan(
    const float* __restrict__ xproj, const float* __restrict__ Wss,
    const float* __restrict__ Wssb, u16* __restrict__ hsb) {
  __shared__ float hbuf[2][2][64];   // [batch-half][buf][state]

  int tid = threadIdx.x;
  int w = tid >> 6, l = tid & 63;
  int bb = w >> 2, wv = w & 3;       // batch-within-block, wave-within-batch
  int b = blockIdx.x * 2 + bb;
  int oo = l >> 2, ks = l & 3;
  int jj = wv * 16 + oo;             // state this quad computes
  int ks16 = ks * 16;

  // weights: 4 gate-rows of state jj, k-slice [16ks,16ks+16) -> 64 VGPRs
  f32x2 wr[32];
#pragma unroll
  for (int g = 0; g < 4; g++) {
    const f32x2* pw = (const f32x2*)(Wss + (size_t)(g * 64 + jj) * 64 + ks16);
#pragma unroll
    for (int q = 0; q < 8; q++) wr[g * 8 + q] = pw[q];
  }
  float mybias = Wssb[ks * 64 + jj];

  float kk = (ks == 2) ? 2.885390082f : -1.442695041f;
  float Ac = (ks == 2) ? 1.f : 0.f;
  float Bc = (ks == 2) ? -2.f : 1.f;

  const float* xqp = xproj + (size_t)b * SSEQ * 256 + ks * 64 + jj;
  float xs0 = xqp[0 * 256];
  float xs1 = xqp[1 * 256];
  float xs2 = xqp[2 * 256];
  float xs3 = xqp[3 * 256];

  u16* hout = hsb + (size_t)b * SSEQ * 64 + jj;

  if (tid < 256) ((float*)hbuf)[tid] = 0.f;
  __syncthreads();

  float c = 0.f;   // state jj's cell, replicated across the quad

#define STEP(T, XS, RB, WB) { \
    f32x4 h4[4]; \
    const f32x4* hb = (const f32x4*)&hbuf[bb][RB][ks16]; \
    h4[0] = hb[0]; h4[1] = hb[1]; h4[2] = hb[2]; h4[3] = hb[3]; \
    float p[4]; \
    _Pragma("unroll") \
    for (int g = 0; g < 4; g++) { \
      f32x2 a0 = (f32x2){0.f, 0.f}, a1 = (f32x2){0.f, 0.f}; \
      _Pragma("unroll") \
      for (int q = 0; q < 4; q++) { \
        f32x2 hA = (f32x2){h4[q][0], h4[q][1]}; \
        f32x2 hB = (f32x2){h4[q][2], h4[q][3]}; \
        a0 = pkfma(hA, wr[g * 8 + 2 * q], a0); \
        a1 = pkfma(hB, wr[g * 8 + 2 * q + 1], a1); \
      } \
      f32x2 ps = a0 + a1; \
      p[g] = ps[0] + ps[1]; \
    } \
    _Pragma("unroll") \
    for (int g = 0; g < 4; g++) p[g] = qadd<0x4E>(qadd<0xB1>(p[g])); \
    float myp = (ks == 1) ? p[1] : p[0]; \
    myp = (ks == 2) ? p[2] : myp; \
    myp = (ks == 3) ? p[3] : myp; \
    float aa = myp + XS + mybias; \
    if ((T) + 4 < SSEQ) XS = xqp[(size_t)((T) + 4) * 256]; \
    float z = exp2f(kk * aa); \
    float act = fmaf(Bc, __builtin_amdgcn_rcpf(z + 1.f), Ac); \
    float fg = qbcast<0x00>(act); \
    float ig = qbcast<0x55>(act); \
    float gg = qbcast<0xAA>(act); \
    float og = qbcast<0xFF>(act); \
    c = fmaf(c, fg, ig * gg); \
    float hn = og * c;  /* faithful to reference: no tanh(c) */ \
    if (ks == 0) { \
      hbuf[bb][WB][jj] = hn; \
      __builtin_nontemporal_store(f2bf(hn), hout + (size_t)(T) * 64); \
    } \
    asm volatile("s_waitcnt lgkmcnt(0)\n\ts_barrier" ::: "memory"); \
  }

  for (int t = 0; t < SSEQ; t += 4) {
    STEP(t + 0, xs0, 1, 0)
    STEP(t + 1, xs1, 0, 1)
    STEP(t + 2, xs2, 1, 0)
    STEP(t + 3, xs3, 0, 1)
  }
#undef STEP
}

// ---------------- K3: y = hs @ Wsy^T + b   (bf16 MFMA, swapped operands) -------
__global__ __launch_bounds__(256) void k3_y(
    const u16* __restrict__ hsb, const u16* __restrict__ wsyb,
    const float* __restrict__ bias, float* __restrict__ y) {
  int bid = blockIdx.x;
  int mb = bid / 79, vb = bid - mb * 79;
  int tid = threadIdx.x, l = tid & 63, wid = tid >> 6;
  int wm = wid >> 1, wv = wid & 1;
  int m0 = mb * 128 + wm * 64, v0 = vb * 128 + wv * 64;
  int lr = l & 15, lg = l >> 4;

  f32x4 acc[4][4];  // [fv][fm]
#pragma unroll
  for (int a = 0; a < 4; a++)
#pragma unroll
    for (int bq = 0; bq < 4; bq++) acc[a][bq] = (f32x4){0.f, 0.f, 0.f, 0.f};

#pragma unroll
  for (int ks = 0; ks < 2; ks++) {
    short8 af[4], bf_[4];
#pragma unroll
    for (int fm = 0; fm < 4; fm++)
      af[fm] = *(const short8*)(hsb + (size_t)(m0 + fm * 16 + lr) * 64 + ks * 32 + lg * 8);
#pragma unroll
    for (int fv = 0; fv < 4; fv++)
      bf_[fv] = *(const short8*)(wsyb + (size_t)(v0 + fv * 16 + lr) * 64 + ks * 32 + lg * 8);
#pragma unroll
    for (int fv = 0; fv < 4; fv++)
#pragma unroll
      for (int fm = 0; fm < 4; fm++)
        acc[fv][fm] = __builtin_amdgcn_mfma_f32_16x16x32_bf16(bf_[fv], af[fm], acc[fv][fm], 0, 0, 0);
  }

#pragma unroll
  for (int fv = 0; fv < 4; fv++) {
    int vb4 = v0 + fv * 16 + lg * 4;
    bool ok = (vb4 + 3) < VV;
    float4 bv = ok ? *(const float4*)(bias + vb4) : float4{0.f, 0.f, 0.f, 0.f};
#pragma unroll
    for (int fm = 0; fm < 4; fm++) {
      int m = m0 + fm * 16 + lr;
      if (ok) {
        float4 o;
        o.x = acc[fv][fm][0] + bv.x;
        o.y = acc[fv][fm][1] + bv.y;
        o.z = acc[fv][fm][2] + bv.z;
        o.w = acc[fv][fm][3] + bv.w;
        *(float4*)(y + (size_t)m * (size_t)VV + vb4) = o;
      }
    }
  }
}

extern "C" void kernel_launch(void* const* d_in, const int* in_sizes, int n_in,
                              void* d_out, int out_size, void* d_ws, size_t ws_size,
                              hipStream_t stream) {
  const float* x     = (const float*)d_in[0];
  const float* Wxs_w = (const float*)d_in[1];
  const float* Wxs_b = (const float*)d_in[2];
  const float* Wss_w = (const float*)d_in[3];
  const float* Wss_b = (const float*)d_in[4];
  const float* Wsy_w = (const float*)d_in[5];
  const float* Wsy_b = (const float*)d_in[6];
  float* y = (float*)d_out;
  char* ws = (char*)d_ws;

  u16*   xhi   = (u16*)(ws + OFF_XHI);
  u16*   xlo   = (u16*)(ws + OFF_XLO);
  u16*   whi   = (u16*)(ws + OFF_WHI);
  u16*   wlo   = (u16*)(ws + OFF_WLO);
  u16*   wsyb  = (u16*)(ws + OFF_WSY);
  float* xproj = (float*)(ws + OFF_XPROJ);
  u16*   hsb   = (u16*)(ws + OFF_HS);

  k0_convert<<<(NX + NW + NP) / 256, 256, 0, stream>>>(x, Wxs_w, Wsy_w, xhi, xlo, whi, wlo, wsyb);
  k1_xproj<<<128, 256, 0, stream>>>(xhi, xlo, whi, wlo, Wxs_b, xproj);
  k2_scan<<<8, 512, 0, stream>>>(xproj, Wss_w, Wss_b, hsb);
  k3_y<<<64 * 79, 256, 0, stream>>>(hsb, wsyb, Wsy_b, y);
}

// Round 14
// 343.237 us; speedup vs baseline: 1.0265x; 1.0265x over previous
//
#include <hip/hip_runtime.h>

typedef unsigned short u16;
typedef unsigned int u32;

using short8 = __attribute__((ext_vector_type(8))) short;
using f32x4  = __attribute__((ext_vector_type(4))) float;
using f32x2  = __attribute__((ext_vector_type(2))) float;

#define SSEQ 512
#define BB   16
#define DD   256
#define G4   256      // 4*SS
#define SSZ  64       // SS
#define VV   10000
#define VPAD 10112    // 79*128
#define MALL 8192     // BB*SSEQ

// ---- ws layout (bytes) ----
#define OFF_XHI   0u
#define OFF_XLO   4194304u
#define OFF_WHI   8388608u
#define OFF_WLO   8519680u
#define OFF_WSY   8650752u
#define OFF_XPROJ 9945088u
#define OFF_HS    18333696u

__device__ __forceinline__ u16 f2bf(float f) {
  u32 u = __float_as_uint(f);
  u32 r = (u + 0x7fffu + ((u >> 16) & 1u)) >> 16;
  return (u16)r;
}
__device__ __forceinline__ float bf2f(u16 h) {
  return __uint_as_float(((u32)h) << 16);
}
// packed dual-FMA: c += a*b elementwise
__device__ __forceinline__ f32x2 pkfma(f32x2 a, f32x2 b, f32x2 c) {
  asm("v_pk_fma_f32 %0, %1, %2, %0" : "+v"(c) : "v"(a), "v"(b));
  return c;
}
// quad butterfly add via DPP; CTRL 0xB1=xor1, 0x4E=xor2
template <int CTRL>
__device__ __forceinline__ float qadd(float x) {
  int pv = __builtin_amdgcn_update_dpp(0, __float_as_int(x), CTRL, 0xf, 0xf, true);
  return x + __int_as_float(pv);
}
// quad broadcast of lane: 0x00/0x55/0xAA/0xFF
template <int CTRL>
__device__ __forceinline__ float qbcast(float x) {
  int pv = __builtin_amdgcn_update_dpp(0, __float_as_int(x), CTRL, 0xf, 0xf, true);
  return __int_as_float(pv);
}

// ---------------- K0: fp32 -> bf16 (hi/lo split for x, Wxs; padded bf16 Wsy) ----
#define NX 2097152
#define NW 65536
#define NP 647168   // VPAD*64
__global__ void k0_convert(const float* __restrict__ x, const float* __restrict__ Wxs,
                           const float* __restrict__ Wsy,
                           u16* __restrict__ xhi, u16* __restrict__ xlo,
                           u16* __restrict__ whi, u16* __restrict__ wlo,
                           u16* __restrict__ wsyb) {
  int i = blockIdx.x * 256 + threadIdx.x;
  if (i < NX) {
    float v = x[i]; u16 h = f2bf(v);
    xhi[i] = h; xlo[i] = f2bf(v - bf2f(h));
  } else if (i < NX + NW) {
    int j = i - NX;
    float v = Wxs[j]; u16 h = f2bf(v);
    whi[j] = h; wlo[j] = f2bf(v - bf2f(h));
  } else if (i < NX + NW + NP) {
    int j = i - NX - NW;
    wsyb[j] = (j < VV * SSZ) ? f2bf(Wsy[j]) : (u16)0;
  }
}

// ---------------- K1: xproj = x @ Wxs^T + b   (double-bf16 MFMA, fp32 out) ------
__global__ __launch_bounds__(256) void k1_xproj(
    const u16* __restrict__ xhi, const u16* __restrict__ xlo,
    const u16* __restrict__ whi, const u16* __restrict__ wlo,
    const float* __restrict__ bias, float* __restrict__ xproj) {
  int bid = blockIdx.x;
  int mb = bid >> 1, nb = bid & 1;
  int tid = threadIdx.x, l = tid & 63, wid = tid >> 6;
  int wm = wid >> 1, wv = wid & 1;
  int m0 = mb * 128 + wm * 64, n0 = nb * 128 + wv * 64;
  int lr = l & 15, lg = l >> 4;

  f32x4 acc[4][4];
#pragma unroll
  for (int a = 0; a < 4; a++)
#pragma unroll
    for (int bq = 0; bq < 4; bq++) acc[a][bq] = (f32x4){0.f, 0.f, 0.f, 0.f};

#pragma unroll
  for (int p = 0; p < 3; p++) {
    const u16* A = (p == 1) ? xlo : xhi;
    const u16* B = (p == 2) ? wlo : whi;
#pragma unroll
    for (int ks = 0; ks < 8; ks++) {
      short8 af[4], bf_[4];
#pragma unroll
      for (int fm = 0; fm < 4; fm++)
        af[fm] = *(const short8*)(A + (size_t)(m0 + fm * 16 + lr) * 256 + ks * 32 + lg * 8);
#pragma unroll
      for (int fv = 0; fv < 4; fv++)
        bf_[fv] = *(const short8*)(B + (size_t)(n0 + fv * 16 + lr) * 256 + ks * 32 + lg * 8);
#pragma unroll
      for (int fm = 0; fm < 4; fm++)
#pragma unroll
        for (int fv = 0; fv < 4; fv++)
          acc[fm][fv] = __builtin_amdgcn_mfma_f32_16x16x32_bf16(af[fm], bf_[fv], acc[fm][fv], 0, 0, 0);
    }
  }
#pragma unroll
  for (int fv = 0; fv < 4; fv++) {
    int j = n0 + fv * 16 + lr;
    float bj = bias[j];
#pragma unroll
    for (int fm = 0; fm < 4; fm++)
#pragma unroll
      for (int r = 0; r < 4; r++) {
        int m = m0 + fm * 16 + lg * 4 + r;
        xproj[(size_t)m * 256 + j] = acc[fm][fv][r] + bj;
      }
  }
}

// ---------------- K2: serial LSTM scan. 8 blocks x 512 thr (2 batches/block) ---
// 2 waves/SIMD from INDEPENDENT batches; amdgpu_waves_per_eu(2,2) pins the
// register allocator's occupancy target so the 64 weight-VGPRs/lane stay
// resident (without it the heuristic shrank to 56 VGPRs and reloaded weights
// every step — R6/R11 failure). One lgkm barrier/step; 4-deep xp prefetch;
// h written fire-and-forget (no vmcnt drain in loop).
__global__ __launch_bounds__(512, 1) __attribute__((amdgpu_waves_per_eu(2, 2)))
void k2_scan(
    const float* __restrict__ xproj, const float* __restrict__ Wss,
    const float* __restrict__ Wssb, u16* __restrict__ hsb) {
  __shared__ float hbuf[2][2][64];   // [batch-half][buf][state]

  int tid = threadIdx.x;
  int w = tid >> 6, l = tid & 63;
  int bb = w >> 2, wv = w & 3;       // batch-within-block, wave-within-batch
  int b = blockIdx.x * 2 + bb;
  int oo = l >> 2, ks = l & 3;
  int jj = wv * 16 + oo;             // state this quad computes
  int ks16 = ks * 16;

  // weights: 4 gate-rows of state jj, k-slice [16ks,16ks+16) -> 64 VGPRs
  f32x2 wr[32];
#pragma unroll
  for (int g = 0; g < 4; g++) {
    const f32x2* pw = (const f32x2*)(Wss + (size_t)(g * 64 + jj) * 64 + ks16);
#pragma unroll
    for (int q = 0; q < 8; q++) wr[g * 8 + q] = pw[q];
  }
  float mybias = Wssb[ks * 64 + jj];

  float kk = (ks == 2) ? 2.885390082f : -1.442695041f;
  float Ac = (ks == 2) ? 1.f : 0.f;
  float Bc = (ks == 2) ? -2.f : 1.f;

  const float* xqp = xproj + (size_t)b * SSEQ * 256 + ks * 64 + jj;
  float xs0 = xqp[0 * 256];
  float xs1 = xqp[1 * 256];
  float xs2 = xqp[2 * 256];
  float xs3 = xqp[3 * 256];

  u16* hout = hsb + (size_t)b * SSEQ * 64 + jj;

  if (tid < 256) ((float*)hbuf)[tid] = 0.f;
  __syncthreads();

  float c = 0.f;   // state jj's cell, replicated across the quad

#define STEP(T, XS, RB, WB) { \
    f32x4 h4[4]; \
    const f32x4* hb = (const f32x4*)&hbuf[bb][RB][ks16]; \
    h4[0] = hb[0]; h4[1] = hb[1]; h4[2] = hb[2]; h4[3] = hb[3]; \
    float p[4]; \
    _Pragma("unroll") \
    for (int g = 0; g < 4; g++) { \
      f32x2 a0 = (f32x2){0.f, 0.f}, a1 = (f32x2){0.f, 0.f}; \
      _Pragma("unroll") \
      for (int q = 0; q < 4; q++) { \
        f32x2 hA = (f32x2){h4[q][0], h4[q][1]}; \
        f32x2 hB = (f32x2){h4[q][2], h4[q][3]}; \
        a0 = pkfma(hA, wr[g * 8 + 2 * q], a0); \
        a1 = pkfma(hB, wr[g * 8 + 2 * q + 1], a1); \
      } \
      f32x2 ps = a0 + a1; \
      p[g] = ps[0] + ps[1]; \
    } \
    _Pragma("unroll") \
    for (int g = 0; g < 4; g++) p[g] = qadd<0x4E>(qadd<0xB1>(p[g])); \
    float myp = (ks == 1) ? p[1] : p[0]; \
    myp = (ks == 2) ? p[2] : myp; \
    myp = (ks == 3) ? p[3] : myp; \
    float aa = myp + XS + mybias; \
    if ((T) + 4 < SSEQ) XS = xqp[(size_t)((T) + 4) * 256]; \
    float z = exp2f(kk * aa); \
    float act = fmaf(Bc, __builtin_amdgcn_rcpf(z + 1.f), Ac); \
    float fg = qbcast<0x00>(act); \
    float ig = qbcast<0x55>(act); \
    float gg = qbcast<0xAA>(act); \
    float og = qbcast<0xFF>(act); \
    c = fmaf(c, fg, ig * gg); \
    float hn = og * c;  /* faithful to reference: no tanh(c) */ \
    if (ks == 0) { \
      hbuf[bb][WB][jj] = hn; \
      __builtin_nontemporal_store(f2bf(hn), hout + (size_t)(T) * 64); \
    } \
    asm volatile("s_waitcnt lgkmcnt(0)\n\ts_barrier" ::: "memory"); \
  }

  for (int t = 0; t < SSEQ; t += 4) {
    STEP(t + 0, xs0, 1, 0)
    STEP(t + 1, xs1, 0, 1)
    STEP(t + 2, xs2, 1, 0)
    STEP(t + 3, xs3, 0, 1)
  }
#undef STEP
}

// ---------------- K3: y = hs @ Wsy^T + b   (bf16 MFMA + LDS-staged epilogue) ---
// MFMA as before (acc: 4 consecutive v per lane), but the tile is staged in
// padded LDS [128][132] and written out as 512B-contiguous row segments
// (32 lanes x float4 per row) — direct acc stores only gave 64B segments
// (half a 128B line -> ~3.2 TB/s effective).
__global__ __launch_bounds__(256) void k3_y(
    const u16* __restrict__ hsb, const u16* __restrict__ wsyb,
    const float* __restrict__ bias, float* __restrict__ y) {
  __shared__ float ltile[128][132];
  int bid = blockIdx.x;
  int mb = bid / 79, vb = bid - mb * 79;
  int tid = threadIdx.x, l = tid & 63, wid = tid >> 6;
  int wm = wid >> 1, wv = wid & 1;
  int m0 = mb * 128 + wm * 64, v0 = vb * 128 + wv * 64;
  int lr = l & 15, lg = l >> 4;

  f32x4 acc[4][4];  // [fv][fm]
#pragma unroll
  for (int a = 0; a < 4; a++)
#pragma unroll
    for (int bq = 0; bq < 4; bq++) acc[a][bq] = (f32x4){0.f, 0.f, 0.f, 0.f};

#pragma unroll
  for (int ks = 0; ks < 2; ks++) {
    short8 af[4], bf_[4];
#pragma unroll
    for (int fm = 0; fm < 4; fm++)
      af[fm] = *(const short8*)(hsb + (size_t)(m0 + fm * 16 + lr) * 64 + ks * 32 + lg * 8);
#pragma unroll
    for (int fv = 0; fv < 4; fv++)
      bf_[fv] = *(const short8*)(wsyb + (size_t)(v0 + fv * 16 + lr) * 64 + ks * 32 + lg * 8);
#pragma unroll
    for (int fv = 0; fv < 4; fv++)
#pragma unroll
      for (int fm = 0; fm < 4; fm++)
        acc[fv][fm] = __builtin_amdgcn_mfma_f32_16x16x32_bf16(bf_[fv], af[fm], acc[fv][fm], 0, 0, 0);
  }

  // stage tile in LDS: local m = wm*64+fm*16+lr, local v = wv*64+fv*16+lg*4
#pragma unroll
  for (int fv = 0; fv < 4; fv++) {
    int vl = wv * 64 + fv * 16 + lg * 4;
    float bv0 = bias[v0 - wv * 64 + vl];   // = bias[vb*128 + vl] (vb*128+vl < 10112; bias padded? no —
    // guard: vb*128+vl can reach 10108 at vb=78; VV=10000. Read guarded:
    bv0 = (vb * 128 + vl < VV) ? bias[vb * 128 + vl] : 0.f;
    float bv1 = (vb * 128 + vl + 1 < VV) ? bias[vb * 128 + vl + 1] : 0.f;
    float bv2 = (vb * 128 + vl + 2 < VV) ? bias[vb * 128 + vl + 2] : 0.f;
    float bv3 = (vb * 128 + vl + 3 < VV) ? bias[vb * 128 + vl + 3] : 0.f;
#pragma unroll
    for (int fm = 0; fm < 4; fm++) {
      int ml = wm * 64 + fm * 16 + lr;
      ltile[ml][vl + 0] = acc[fv][fm][0] + bv0;
      ltile[ml][vl + 1] = acc[fv][fm][1] + bv1;
      ltile[ml][vl + 2] = acc[fv][fm][2] + bv2;
      ltile[ml][vl + 3] = acc[fv][fm][3] + bv3;
    }
  }
  __syncthreads();

  // write out: 8 rows per iter, 32 lanes x float4 = 512B contiguous per row
  int rr0 = tid >> 5;            // 0..7
  int c4 = (tid & 31) * 4;       // 0..124
#pragma unroll
  for (int it = 0; it < 16; it++) {
    int ml = it * 8 + rr0;
    int m = mb * 128 + ml;
    int v = vb * 128 + c4;
    if (v + 3 < VV) {
      float4 o;
      o.x = ltile[ml][c4 + 0];
      o.y = ltile[ml][c4 + 1];
      o.z = ltile[ml][c4 + 2];
      o.w = ltile[ml][c4 + 3];
      *(float4*)(y + (size_t)m * (size_t)VV + v) = o;
    }
  }
}

extern "C" void kernel_launch(void* const* d_in, const int* in_sizes, int n_in,
                              void* d_out, int out_size, void* d_ws, size_t ws_size,
                              hipStream_t stream) {
  const float* x     = (const float*)d_in[0];
  const float* Wxs_w = (const float*)d_in[1];
  const float* Wxs_b = (const float*)d_in[2];
  const float* Wss_w = (const float*)d_in[3];
  const float* Wss_b = (const float*)d_in[4];
  const float* Wsy_w = (const float*)d_in[5];
  const float* Wsy_b = (const float*)d_in[6];
  float* y = (float*)d_out;
  char* ws = (char*)d_ws;

  u16*   xhi   = (u16*)(ws + OFF_XHI);
  u16*   xlo   = (u16*)(ws + OFF_XLO);
  u16*   whi   = (u16*)(ws + OFF_WHI);
  u16*   wlo   = (u16*)(ws + OFF_WLO);
  u16*   wsyb  = (u16*)(ws + OFF_WSY);
  float* xproj = (float*)(ws + OFF_XPROJ);
  u16*   hsb   = (u16*)(ws + OFF_HS);

  k0_convert<<<(NX + NW + NP) / 256, 256, 0, stream>>>(x, Wxs_w, Wsy_w, xhi, xlo, whi, wlo, wsyb);
  k1_xproj<<<128, 256, 0, stream>>>(xhi, xlo, whi, wlo, Wxs_b, xproj);
  k2_scan<<<8, 512, 0, stream>>>(xproj, Wss_w, Wss_b, hsb);
  k3_y<<<64 * 79, 256, 0, stream>>>(hsb, wsyb, Wsy_b, y);
}

// Round 15
// 338.835 us; speedup vs baseline: 1.0398x; 1.0130x over previous
//
#include <hip/hip_runtime.h>

typedef unsigned short u16;
typedef unsigned int u32;

using short8 = __attribute__((ext_vector_type(8))) short;
using f32x4  = __attribute__((ext_vector_type(4))) float;
using h2     = __attribute__((ext_vector_type(2))) _Float16;

#define SSEQ 512
#define BB   16
#define DD   256
#define G4   256      // 4*SS
#define SSZ  64       // SS
#define VV   10000
#define VPAD 10112    // 79*128
#define MALL 8192     // BB*SSEQ

// ---- ws layout (bytes) ----
#define OFF_XHI   0u
#define OFF_XLO   4194304u
#define OFF_WHI   8388608u
#define OFF_WLO   8519680u
#define OFF_WSY   8650752u
#define OFF_XPROJ 9945088u
#define OFF_HS    18333696u
#define OFF_WPK   19382272u   // 8192 u32 = 32KB packed-f16 Wss

__device__ __forceinline__ u16 f2bf(float f) {
  u32 u = __float_as_uint(f);
  u32 r = (u + 0x7fffu + ((u >> 16) & 1u)) >> 16;
  return (u16)r;
}
__device__ __forceinline__ float bf2f(u16 h) {
  return __uint_as_float(((u32)h) << 16);
}

// ---------------- K0: fp32 -> bf16 conversions + packed-f16 Wss ----------------
#define NX 2097152
#define NW 65536
#define NP 647168   // VPAD*64
#define NF 8192     // 4*64*32 packed pairs of Wss
__global__ void k0_convert(const float* __restrict__ x, const float* __restrict__ Wxs,
                           const float* __restrict__ Wsy, const float* __restrict__ Wss,
                           u16* __restrict__ xhi, u16* __restrict__ xlo,
                           u16* __restrict__ whi, u16* __restrict__ wlo,
                           u16* __restrict__ wsyb, u32* __restrict__ wpk) {
  int i = blockIdx.x * 256 + threadIdx.x;
  if (i < NX) {
    float v = x[i]; u16 h = f2bf(v);
    xhi[i] = h; xlo[i] = f2bf(v - bf2f(h));
  } else if (i < NX + NW) {
    int j = i - NX;
    float v = Wxs[j]; u16 h = f2bf(v);
    whi[j] = h; wlo[j] = f2bf(v - bf2f(h));
  } else if (i < NX + NW + NP) {
    int j = i - NX - NW;
    wsyb[j] = (j < VV * SSZ) ? f2bf(Wsy[j]) : (u16)0;
  } else if (i < NX + NW + NP + NF) {
    int j = i - NX - NW - NP;
    int g = j >> 11, rem = j & 2047;
    int s = rem >> 5, kp = rem & 31;
    int row = g * 64 + s;
    h2 p;
    p[0] = (_Float16)Wss[row * 64 + 2 * kp];
    p[1] = (_Float16)Wss[row * 64 + 2 * kp + 1];
    wpk[j] = *(u32*)&p;
  }
}

// ---------------- K1: xproj = x @ Wxs^T + b   (double-bf16 MFMA, fp32 out) ------
__global__ __launch_bounds__(256) void k1_xproj(
    const u16* __restrict__ xhi, const u16* __restrict__ xlo,
    const u16* __restrict__ whi, const u16* __restrict__ wlo,
    const float* __restrict__ bias, float* __restrict__ xproj) {
  int bid = blockIdx.x;
  int mb = bid >> 1, nb = bid & 1;
  int tid = threadIdx.x, l = tid & 63, wid = tid >> 6;
  int wm = wid >> 1, wv = wid & 1;
  int m0 = mb * 128 + wm * 64, n0 = nb * 128 + wv * 64;
  int lr = l & 15, lg = l >> 4;

  f32x4 acc[4][4];
#pragma unroll
  for (int a = 0; a < 4; a++)
#pragma unroll
    for (int bq = 0; bq < 4; bq++) acc[a][bq] = (f32x4){0.f, 0.f, 0.f, 0.f};

#pragma unroll
  for (int p = 0; p < 3; p++) {
    const u16* A = (p == 1) ? xlo : xhi;
    const u16* B = (p == 2) ? wlo : whi;
#pragma unroll
    for (int ks = 0; ks < 8; ks++) {
      short8 af[4], bf_[4];
#pragma unroll
      for (int fm = 0; fm < 4; fm++)
        af[fm] = *(const short8*)(A + (size_t)(m0 + fm * 16 + lr) * 256 + ks * 32 + lg * 8);
#pragma unroll
      for (int fv = 0; fv < 4; fv++)
        bf_[fv] = *(const short8*)(B + (size_t)(n0 + fv * 16 + lr) * 256 + ks * 32 + lg * 8);
#pragma unroll
      for (int fm = 0; fm < 4; fm++)
#pragma unroll
        for (int fv = 0; fv < 4; fv++)
          acc[fm][fv] = __builtin_amdgcn_mfma_f32_16x16x32_bf16(af[fm], bf_[fv], acc[fm][fv], 0, 0, 0);
    }
  }
#pragma unroll
  for (int fv = 0; fv < 4; fv++) {
    int j = n0 + fv * 16 + lr;
    float bj = bias[j];
#pragma unroll
    for (int fm = 0; fm < 4; fm++)
#pragma unroll
      for (int r = 0; r < 4; r++) {
        int m = m0 + fm * 16 + lg * 4 + r;
        xproj[(size_t)m * 256 + j] = acc[fm][fv][r] + bj;
      }
  }
}

// ---------------- K2: serial LSTM scan. 16 blocks x ONE wave -------------------
// Lane l owns state l: all 4 gate dot-products via packed-f16 v_dot2
// (4 gates x 32 half2 weights = 128 VGPRs — fits; R1's f32 variant needed 256
// and spilled). h exchange: ds_write_b16 own h + 8 wave-uniform ds_read_b128 —
// single wave, so ordering is lgkmcnt(0) only, ZERO barriers, no cross-wave
// traffic, no butterfly/broadcast ops. 2-step xp prefetch (static regs).
__global__ __launch_bounds__(64, 1) void k2_scan(
    const float* __restrict__ xproj, const u32* __restrict__ wpk,
    const float* __restrict__ Wssb, u16* __restrict__ hsb) {
  __shared__ u32 hsh[32];           // 64 f16 h values, packed
  int b = blockIdx.x, l = threadIdx.x;

  // weights: gate g, pair kp -> W[g*64+l][2kp..2kp+1] as half2
  h2 wp[4][32];
#pragma unroll
  for (int g = 0; g < 4; g++) {
    const u32* src = wpk + g * 2048 + l * 32;
#pragma unroll
    for (int kp = 0; kp < 32; kp++) {
      u32 v = src[kp];
      wp[g][kp] = *(h2*)&v;
    }
  }
  float bias4[4];
#pragma unroll
  for (int g = 0; g < 4; g++) bias4[g] = Wssb[g * 64 + l];

  const float* xpb = xproj + (size_t)b * SSEQ * 256 + l;
  float xA[4], xB[4];
#pragma unroll
  for (int g = 0; g < 4; g++) { xA[g] = xpb[g * 64]; xB[g] = xpb[256 + g * 64]; }

  if (l < 32) hsh[l] = 0;
  asm volatile("s_waitcnt lgkmcnt(0)" ::: "memory");

  u16* hout = hsb + (size_t)b * SSEQ * 64 + l;
  float c = 0.f;

#define STEP(T, X) { \
    u32 hw[32]; \
    const uint4* hb4 = (const uint4*)hsh; \
    _Pragma("unroll") \
    for (int q = 0; q < 8; q++) { \
      uint4 r = hb4[q]; \
      hw[4 * q + 0] = r.x; hw[4 * q + 1] = r.y; \
      hw[4 * q + 2] = r.z; hw[4 * q + 3] = r.w; \
    } \
    float a0 = X[0] + bias4[0]; \
    float a1 = X[1] + bias4[1]; \
    float a2 = X[2] + bias4[2]; \
    float a3 = X[3] + bias4[3]; \
    _Pragma("unroll") \
    for (int kp = 0; kp < 32; kp++) { \
      h2 hh = *(h2*)&hw[kp]; \
      a0 = __builtin_amdgcn_fdot2(hh, wp[0][kp], a0, false); \
      a1 = __builtin_amdgcn_fdot2(hh, wp[1][kp], a1, false); \
      a2 = __builtin_amdgcn_fdot2(hh, wp[2][kp], a2, false); \
      a3 = __builtin_amdgcn_fdot2(hh, wp[3][kp], a3, false); \
    } \
    if ((T) + 2 < SSEQ) { \
      const float* xn = xpb + (size_t)((T) + 2) * 256; \
      _Pragma("unroll") \
      for (int g = 0; g < 4; g++) X[g] = xn[g * 64]; \
    } \
    float fg = __builtin_amdgcn_rcpf(1.f + exp2f(-1.442695041f * a0)); \
    float ig = __builtin_amdgcn_rcpf(1.f + exp2f(-1.442695041f * a1)); \
    float gg = fmaf(-2.f, __builtin_amdgcn_rcpf(exp2f(2.885390082f * a2) + 1.f), 1.f); \
    float og = __builtin_amdgcn_rcpf(1.f + exp2f(-1.442695041f * a3)); \
    c = fmaf(c, fg, ig * gg); \
    float hn = og * c;   /* faithful to reference: no tanh(c) */ \
    _Float16 hf = (_Float16)hn; \
    ((u16*)hsh)[l] = *(u16*)&hf; \
    hout[(size_t)(T) * 64] = f2bf(hn);   /* fire-and-forget */ \
    asm volatile("s_waitcnt lgkmcnt(0)" ::: "memory"); \
  }

  for (int t = 0; t < SSEQ; t += 2) {
    STEP(t, xA)
    STEP(t + 1, xB)
  }
#undef STEP
}

// ---------------- K3: y = hs @ Wsy^T + b   (bf16 MFMA + LDS-staged epilogue) ---
__global__ __launch_bounds__(256) void k3_y(
    const u16* __restrict__ hsb, const u16* __restrict__ wsyb,
    const float* __restrict__ bias, float* __restrict__ y) {
  __shared__ float ltile[128][132];
  int bid = blockIdx.x;
  int mb = bid / 79, vb = bid - mb * 79;
  int tid = threadIdx.x, l = tid & 63, wid = tid >> 6;
  int wm = wid >> 1, wv = wid & 1;
  int m0 = mb * 128 + wm * 64, v0 = vb * 128 + wv * 64;
  int lr = l & 15, lg = l >> 4;

  f32x4 acc[4][4];  // [fv][fm]
#pragma unroll
  for (int a = 0; a < 4; a++)
#pragma unroll
    for (int bq = 0; bq < 4; bq++) acc[a][bq] = (f32x4){0.f, 0.f, 0.f, 0.f};

#pragma unroll
  for (int ks = 0; ks < 2; ks++) {
    short8 af[4], bf_[4];
#pragma unroll
    for (int fm = 0; fm < 4; fm++)
      af[fm] = *(const short8*)(hsb + (size_t)(m0 + fm * 16 + lr) * 64 + ks * 32 + lg * 8);
#pragma unroll
    for (int fv = 0; fv < 4; fv++)
      bf_[fv] = *(const short8*)(wsyb + (size_t)(v0 + fv * 16 + lr) * 64 + ks * 32 + lg * 8);
#pragma unroll
    for (int fv = 0; fv < 4; fv++)
#pragma unroll
      for (int fm = 0; fm < 4; fm++)
        acc[fv][fm] = __builtin_amdgcn_mfma_f32_16x16x32_bf16(bf_[fv], af[fm], acc[fv][fm], 0, 0, 0);
  }

  // stage tile in LDS (guarded bias reads)
#pragma unroll
  for (int fv = 0; fv < 4; fv++) {
    int vl = wv * 64 + fv * 16 + lg * 4;
    float bv0 = (vb * 128 + vl     < VV) ? bias[vb * 128 + vl]     : 0.f;
    float bv1 = (vb * 128 + vl + 1 < VV) ? bias[vb * 128 + vl + 1] : 0.f;
    float bv2 = (vb * 128 + vl + 2 < VV) ? bias[vb * 128 + vl + 2] : 0.f;
    float bv3 = (vb * 128 + vl + 3 < VV) ? bias[vb * 128 + vl + 3] : 0.f;
#pragma unroll
    for (int fm = 0; fm < 4; fm++) {
      int ml = wm * 64 + fm * 16 + lr;
      ltile[ml][vl + 0] = acc[fv][fm][0] + bv0;
      ltile[ml][vl + 1] = acc[fv][fm][1] + bv1;
      ltile[ml][vl + 2] = acc[fv][fm][2] + bv2;
      ltile[ml][vl + 3] = acc[fv][fm][3] + bv3;
    }
  }
  __syncthreads();

  // write out: 512B-contiguous row segments (32 lanes x float4)
  int rr0 = tid >> 5;
  int c4 = (tid & 31) * 4;
#pragma unroll
  for (int it = 0; it < 16; it++) {
    int ml = it * 8 + rr0;
    int m = mb * 128 + ml;
    int v = vb * 128 + c4;
    if (v + 3 < VV) {
      float4 o;
      o.x = ltile[ml][c4 + 0];
      o.y = ltile[ml][c4 + 1];
      o.z = ltile[ml][c4 + 2];
      o.w = ltile[ml][c4 + 3];
      *(float4*)(y + (size_t)m * (size_t)VV + v) = o;
    }
  }
}

extern "C" void kernel_launch(void* const* d_in, const int* in_sizes, int n_in,
                              void* d_out, int out_size, void* d_ws, size_t ws_size,
                              hipStream_t stream) {
  const float* x     = (const float*)d_in[0];
  const float* Wxs_w = (const float*)d_in[1];
  const float* Wxs_b = (const float*)d_in[2];
  const float* Wss_w = (const float*)d_in[3];
  const float* Wss_b = (const float*)d_in[4];
  const float* Wsy_w = (const float*)d_in[5];
  const float* Wsy_b = (const float*)d_in[6];
  float* y = (float*)d_out;
  char* ws = (char*)d_ws;

  u16*   xhi   = (u16*)(ws + OFF_XHI);
  u16*   xlo   = (u16*)(ws + OFF_XLO);
  u16*   whi   = (u16*)(ws + OFF_WHI);
  u16*   wlo   = (u16*)(ws + OFF_WLO);
  u16*   wsyb  = (u16*)(ws + OFF_WSY);
  float* xproj = (float*)(ws + OFF_XPROJ);
  u16*   hsb   = (u16*)(ws + OFF_HS);
  u32*   wpk   = (u32*)(ws + OFF_WPK);

  k0_convert<<<(NX + NW + NP + NF) / 256, 256, 0, stream>>>(
      x, Wxs_w, Wsy_w, Wss_w, xhi, xlo, whi, wlo, wsyb, wpk);
  k1_xproj<<<128, 256, 0, stream>>>(xhi, xlo, whi, wlo, Wxs_b, xproj);
  k2_scan<<<16, 64, 0, stream>>>(xproj, wpk, Wss_b, hsb);
  k3_y<<<64 * 79, 256, 0, stream>>>(hsb, wsyb, Wsy_b, y);
}